// Round 14
// baseline (172.392 us; speedup 1.0000x reference)
//
#include <hip/hip_runtime.h>
#include <math.h>

#define KNN    10
#define NPTS   8192
#define HID    64
#define NF     76
#define Q      16                // queries per block (one group)
#define CAP    64                // pass-2 collection capacity per query
#define F32_INF __uint_as_float(0x7F800000u)

typedef float v2f __attribute__((ext_vector_type(2)));

__device__ __forceinline__ float rl(float v, int lane) {
    return __int_as_float(__builtin_amdgcn_readlane(__float_as_int(v), lane));
}

// ---------------------------------------------------------------------------
// R24 SoA transpose (kept: candidate loads coalesced).
// ---------------------------------------------------------------------------
__global__ __launch_bounds__(256) void soa_kernel(const float* __restrict__ cloud,
                                                  float* __restrict__ soa) {
    const int i = blockIdx.x * 256 + threadIdx.x;   // 0..32767 (grid exact)
    const float x = cloud[i * 3 + 0];
    const float y = cloud[i * 3 + 1];
    const float z = cloud[i * 3 + 2];
    soa[i]             = x;
    soa[4 * NPTS + i]  = y;
    soa[8 * NPTS + i]  = z;
}

// ---------------------------------------------------------------------------
// R33: pass2 branch consolidation. Asymmetry in the 12-round ledger: REMOVING
// issue never helped (R22 -19% VALU -> dt~0, pass1 at its latency floor) but
// ADDING issue always hurt (R23/R25/R31) — and pass2 (64us) runs 45% over
// pass1 (44us) with the same scan skeleton. The delta is pass2's per-tile
// 16 v_cmp + 16 divergent branch sequences (s_and_saveexec/s_cbranch per
// query). So pass2 is ABOVE the floor: its extra instructions pay full
// price. Fix: compute the 8 packed distances into registers, form
// margin = min_j(v_j - tau_j) (8 pk_sub + 7 pk_min + 1 min), and wrap all
// 16 checks in ONE rare branch. Sign-equivalence exact (IEEE gradual
// underflow: v-t<=0 <=> v<=t; no NaNs); pre-filter is conservative and the
// authoritative per-pair checks inside are byte-identical -> same hits,
// same keys, same selection -> absmax must remain 0.004394531.
// Pre-committed: pass2 >= 62us -> pass2 also at the floor -> accept.
// pass1 / soa / feat_mlp byte-for-byte unchanged (R29/R32 form).
// ---------------------------------------------------------------------------
__global__ __launch_bounds__(256) void knn_pass1(const float* __restrict__ soa,
                                                 float* __restrict__ tau_g) {
    __shared__ float pk[4][Q][17];                  // 4.3 KB

    const int t    = threadIdx.x;
    const int w    = t >> 6;                  // wave 0..3 = candidate quarter
    const int lane = t & 63;
    const int bx   = blockIdx.x;              // 0..2047
    const int b    = bx >> 9;                 // batch (512 blocks per batch)
    const int n_base = (bx & 511) * Q;        // batch-local first query
    const int cb0 = w * (NPTS / 4);           // candidate base for this wave

    const float* __restrict__ xs = soa + (size_t)b * NPTS;
    const float* __restrict__ ys = xs + 4 * NPTS;
    const float* __restrict__ zs = xs + 8 * NPTS;

    // ---- query coords -> SGPR pairs via readlane ----
    v2f qx_p[8], qy_p[8], qz_p[8];
    {
        const int ql = n_base + (lane & 15);
        const float lx = xs[ql];
        const float ly = ys[ql];
        const float lz = zs[ql];
#pragma unroll
        for (int j = 0; j < 8; ++j) {
            qx_p[j] = (v2f){ rl(lx, 2 * j), rl(lx, 2 * j + 1) };
            qy_p[j] = (v2f){ rl(ly, 2 * j), rl(ly, 2 * j + 1) };
            qz_p[j] = (v2f){ rl(lz, 2 * j), rl(lz, 2 * j + 1) };
        }
    }

#define LOADT(TI, RX, RY, RZ) do {                        \
        const int c_ = cb0 + (((TI) & 31) * 64) + lane;   \
        (RX) = xs[c_]; (RY) = ys[c_]; (RZ) = zs[c_];      \
    } while (0)

#define P1_BODY(CX, CY, CZ) do {                                          \
        const float aw_ = fmaf((CZ), (CZ), fmaf((CY), (CY), (CX)*(CX)));  \
        const v2f aw2_ = (v2f){ aw_, aw_ };                               \
        const v2f ax2_ = (v2f){ -2.0f * (CX), -2.0f * (CX) };             \
        const v2f ay2_ = (v2f){ -2.0f * (CY), -2.0f * (CY) };             \
        const v2f az2_ = (v2f){ -2.0f * (CZ), -2.0f * (CZ) };             \
        _Pragma("unroll")                                                 \
        for (int j_ = 0; j_ < 8; ++j_) {                                  \
            const v2f v_ = __builtin_elementwise_fma(ax2_, qx_p[j_],      \
                           __builtin_elementwise_fma(ay2_, qy_p[j_],      \
                           __builtin_elementwise_fma(az2_, qz_p[j_], aw2_))); \
            vmin2[j_] = __builtin_elementwise_min(vmin2[j_], v_);         \
        }                                                                 \
    } while (0)

    v2f vmin2[8];
#pragma unroll
    for (int j = 0; j < 8; ++j) vmin2[j] = (v2f){ F32_INF, F32_INF };

    {
        float x0, y0, z0, x1, y1, z1, x2, y2, z2, x3, y3, z3;
        LOADT(0, x0, y0, z0);
        LOADT(1, x1, y1, z1);
        for (int k = 0; k < 32; k += 4) {     // 8 iterations, 4 tiles each
            LOADT(k + 2, x2, y2, z2);
            LOADT(k + 3, x3, y3, z3);
            P1_BODY(x0, y0, z0);
            P1_BODY(x1, y1, z1);
            LOADT(k + 4, x0, y0, z0);         // wraps at tail (dead)
            LOADT(k + 5, x1, y1, z1);
            P1_BODY(x2, y2, z2);
            P1_BODY(x3, y3, z3);
        }
    }

#pragma unroll
    for (int qq = 0; qq < Q; ++qq) {
        float v = vmin2[qq >> 1][qq & 1];
        v = fminf(v, __shfl_xor(v, 32, 64));
        v = fminf(v, __shfl_xor(v, 16, 64));
        if (lane < 16) pk[w][qq][lane] = v;
    }
    __syncthreads();                          // pk visible

    // wave 0: 11th smallest of 64 chunk minima -> tau (exact bits to global)
    if (w == 0) {
        float md[KNN + 1];
#pragma unroll
        for (int s = 0; s <= KNN; ++s) md[s] = F32_INF;
        const int qsel = lane & 15;           // 4-way replicated
#pragma unroll
        for (int cc = 0; cc < 64; ++cc) {
            float d = pk[cc >> 4][qsel][cc & 15];
#pragma unroll
            for (int u = 0; u <= KNN; ++u) {
                const float lo = fminf(md[u], d);
                d = fmaxf(md[u], d);
                md[u] = lo;
            }
        }
        if (lane < 16) tau_g[bx * Q + lane] = md[KNN] + 1e-3f;
    }
#undef LOADT
#undef P1_BODY
}

__global__ __launch_bounds__(256) void knn_pass2(const float* __restrict__ soa,
                                                 const float* __restrict__ tau_g,
                                                 unsigned short* __restrict__ knn_idx) {
    __shared__ unsigned long long coll[CAP][Q + 1]; // 8.5 KB
    __shared__ int cnt[Q];

    const int t    = threadIdx.x;
    const int w    = t >> 6;                  // wave 0..3 = candidate quarter
    const int lane = t & 63;
    const int bx   = blockIdx.x;              // 0..2047
    const int b    = bx >> 9;                 // batch
    const int n_base = (bx & 511) * Q;        // batch-local first query
    const int cb0 = w * (NPTS / 4);           // candidate base for this wave

    const float* __restrict__ xs = soa + (size_t)b * NPTS;
    const float* __restrict__ ys = xs + 4 * NPTS;
    const float* __restrict__ zs = xs + 8 * NPTS;

    if (t < Q) cnt[t] = 0;

    // ---- query coords -> SGPR pairs via readlane ----
    v2f qx_p[8], qy_p[8], qz_p[8];
    {
        const int ql = n_base + (lane & 15);
        const float lx = xs[ql];
        const float ly = ys[ql];
        const float lz = zs[ql];
#pragma unroll
        for (int j = 0; j < 8; ++j) {
            qx_p[j] = (v2f){ rl(lx, 2 * j), rl(lx, 2 * j + 1) };
            qy_p[j] = (v2f){ rl(ly, 2 * j), rl(ly, 2 * j + 1) };
            qz_p[j] = (v2f){ rl(lz, 2 * j), rl(lz, 2 * j + 1) };
        }
    }

    // tau as SGPR v2f pairs (same exact bits as pass1 wrote)
    v2f taum2[8];
    {
        const float tv = tau_g[bx * Q + (lane & 15)];
#pragma unroll
        for (int j = 0; j < 8; ++j)
            taum2[j] = (v2f){ rl(tv, 2 * j), rl(tv, 2 * j + 1) };
    }
    __syncthreads();                          // cnt zero-init visible

#define LOADT(TI, RX, RY, RZ) do {                        \
        const int c_ = cb0 + (((TI) & 31) * 64) + lane;   \
        (RX) = xs[c_]; (RY) = ys[c_]; (RZ) = zs[c_];      \
    } while (0)

#define P2_BODY(CX, CY, CZ, TI) do {                                      \
        const int jj_ = cb0 + (TI) * 64 + lane;                           \
        const float aw_ = fmaf((CZ), (CZ), fmaf((CY), (CY), (CX)*(CX)));  \
        const v2f aw2_ = (v2f){ aw_, aw_ };                               \
        const v2f ax2_ = (v2f){ -2.0f * (CX), -2.0f * (CX) };             \
        const v2f ay2_ = (v2f){ -2.0f * (CY), -2.0f * (CY) };             \
        const v2f az2_ = (v2f){ -2.0f * (CZ), -2.0f * (CZ) };             \
        v2f vv_[8];                                                       \
        _Pragma("unroll")                                                 \
        for (int j_ = 0; j_ < 8; ++j_) {                                  \
            vv_[j_] = __builtin_elementwise_fma(ax2_, qx_p[j_],           \
                      __builtin_elementwise_fma(ay2_, qy_p[j_],           \
                      __builtin_elementwise_fma(az2_, qz_p[j_], aw2_)));  \
        }                                                                 \
        v2f mm_ = vv_[0] - taum2[0];                                      \
        _Pragma("unroll")                                                 \
        for (int j_ = 1; j_ < 8; ++j_)                                    \
            mm_ = __builtin_elementwise_min(mm_, vv_[j_] - taum2[j_]);    \
        if (__builtin_expect(fminf(mm_[0], mm_[1]) <= 0.0f, 0)) {         \
            _Pragma("unroll")                                             \
            for (int j_ = 0; j_ < 8; ++j_) {                              \
                _Pragma("unroll")                                         \
                for (int half_ = 0; half_ < 2; ++half_) {                 \
                    const int qq_ = 2 * j_ + half_;                       \
                    if (vv_[j_][half_] <= taum2[j_][half_]) {             \
                        const float qx_ = qx_p[j_][half_];                \
                        const float qy_ = qy_p[j_][half_];                \
                        const float qz_ = qz_p[j_][half_];                \
                        const float qs_ = fmaf(qz_, qz_, fmaf(qy_, qy_, qx_ * qx_)); \
                        const float dot_ = fmaf((CZ), qz_, fmaf((CY), qy_, (CX) * qx_)); \
                        const float d2_ = fmaf(-2.0f, dot_, qs_ + aw_);   \
                        const unsigned int fb_ = __float_as_uint(d2_);    \
                        const unsigned int m_ =                           \
                            fb_ ^ ((unsigned int)((int)fb_ >> 31) | 0x80000000u); \
                        const unsigned long long key_ =                   \
                            ((unsigned long long)m_ << 13) | (unsigned long long)(unsigned)jj_; \
                        const int slot_ = atomicAdd(&cnt[qq_], 1);        \
                        if (slot_ < CAP) coll[slot_][qq_] = key_;         \
                    }                                                     \
                }                                                         \
            }                                                             \
        }                                                                 \
    } while (0)

    {
        float x0, y0, z0, x1, y1, z1, x2, y2, z2, x3, y3, z3;
        LOADT(0, x0, y0, z0);
        LOADT(1, x1, y1, z1);
        for (int k = 0; k < 32; k += 4) {
            LOADT(k + 2, x2, y2, z2);
            LOADT(k + 3, x3, y3, z3);
            P2_BODY(x0, y0, z0, k + 0);
            P2_BODY(x1, y1, z1, k + 1);
            LOADT(k + 4, x0, y0, z0);
            LOADT(k + 5, x1, y1, z1);
            P2_BODY(x2, y2, z2, k + 2);
            P2_BODY(x3, y3, z3, k + 3);
        }
    }
    __syncthreads();

    // ---------------- phase 3: top-11 bubble, filter self by index ----------
    if (t < Q) {
        const int m = cnt[t];
        int mc = m;
#pragma unroll
        for (int off = 1; off < 16; off <<= 1)        // 16 active lanes only
            mc = max(mc, __shfl_xor(mc, off, 64));
        mc = __builtin_amdgcn_readfirstlane(mc);

        const int n = (bx & 511) * Q + t;     // this lane's batch-local query

        unsigned long long md[KNN + 1];
#pragma unroll
        for (int s = 0; s <= KNN; ++s) md[s] = ~0ULL;

        if (mc <= CAP) {
            for (int cc = 0; cc < mc; ++cc) {
                unsigned long long key = (cc < m) ? coll[cc][t] : ~0ULL;
#pragma unroll
                for (int u = 0; u <= KNN; ++u) {
                    const bool lt = key < md[u];
                    const unsigned long long lo = lt ? key : md[u];
                    key = lt ? md[u] : key;
                    md[u] = lo;
                }
            }
        } else {
            // exact serial fallback (never expected): full rescan (SoA reads,
            // identical float values)
            const float qx = xs[n];
            const float qy = ys[n];
            const float qz = zs[n];
            const float qs = fmaf(qz, qz, fmaf(qy, qy, qx * qx));
            for (int j = 0; j < NPTS; ++j) {
                const float px = xs[j];
                const float py = ys[j];
                const float pz = zs[j];
                const float pw = fmaf(pz, pz, fmaf(py, py, px * px));
                const float dot = fmaf(pz, qz, fmaf(py, qy, px * qx));
                const float d2 = fmaf(-2.0f, dot, qs + pw);
                const unsigned int fb = __float_as_uint(d2);
                const unsigned int mm =
                    fb ^ ((unsigned int)((int)fb >> 31) | 0x80000000u);
                unsigned long long key =
                    ((unsigned long long)mm << 13) | (unsigned long long)j;
                key = (j == n) ? ~0ULL : key;
#pragma unroll
                for (int u = 0; u <= KNN; ++u) {
                    const bool lt = key < md[u];
                    const unsigned long long lo = lt ? key : md[u];
                    key = lt ? md[u] : key;
                    md[u] = lo;
                }
            }
        }

        unsigned short* outp = knn_idx + ((size_t)b * NPTS + n) * KNN;
        int outc = 0;
#pragma unroll
        for (int u = 0; u <= KNN; ++u) {
            const int idx = (int)(md[u] & 8191u);
            if (outc < KNN && idx != n) outp[outc++] = (unsigned short)idx;
        }
    }
#undef LOADT
#undef P2_BODY
}

// ---------------------------------------------------------------------------
// Features + MLP — R19 quad-parallel form (best measured). Lanes own 3/3/2/2
// neighbors; quad shfl_xor(1,2) reduces; eigen redundant on 4 lanes; MLP =
// R12/R14 layout.
// ---------------------------------------------------------------------------
__global__ __launch_bounds__(256) void feat_mlp_kernel(const float* __restrict__ cloud,
                                                       const float* __restrict__ W1,
                                                       const float* __restrict__ b1,
                                                       const float* __restrict__ W2,
                                                       const float* __restrict__ b2,
                                                       const unsigned short* __restrict__ knn_idx,
                                                       float* __restrict__ out) {
    __shared__ float w1s[NF * 68];            // padded stride
    __shared__ float b1s[HID];
    __shared__ float w2s[HID * 3];
    __shared__ float b2s[3];
    __shared__ float fs[64][NF + 1];          // stride 77

    const int t = threadIdx.x;
    for (int idx = t; idx < NF * HID; idx += 256)
        w1s[(idx >> 6) * 68 + (idx & 63)] = W1[idx];
    if (t < HID) b1s[t] = b1[t];
    if (t < HID * 3) w2s[t] = W2[t];
    if (t < 3) b2s[t] = b2[t];

    const int pl   = t >> 2;                  // point slot 0..63
    const int s    = t & 3;                   // quad sub-lane
    const int subh = t & 1;                   // hidden half
    const int subf = (t >> 1) & 1;            // feature half
    const int gid = blockIdx.x * 64 + pl;     // 0..32767
    const int b = gid >> 13;
    const int n = gid & (NPTS - 1);
    const float* cb = cloud + (size_t)b * NPTS * 3;

    // ---- quad-parallel feature build ----
    {
        const float cx = cb[n * 3 + 0];       // same addr across quad (broadcast)
        const float cy = cb[n * 3 + 1];
        const float cz = cb[n * 3 + 2];

        // neighbor ownership: s=0:{0,1,2} s=1:{3,4,5} s=2:{6,7} s=3:{8,9}
        const int kbase = (s == 0) ? 0 : (s == 1) ? 3 : (s == 2) ? 6 : 8;
        const int kcnt  = (s < 2) ? 3 : 2;

        float nx[3], ny[3], nz[3];
        const unsigned short* ki = knn_idx + (size_t)gid * KNN;
        for (int kk = 0; kk < kcnt; ++kk) {
            const int j = ki[kbase + kk];
            nx[kk] = cb[j * 3 + 0];
            ny[kk] = cb[j * 3 + 1];
            nz[kk] = cb[j * 3 + 2];
        }

        float* fr = fs[pl];
        if (s == 0) { fr[0] = cx; fr[1] = cy; fr[2] = cz; }
        for (int kk = 0; kk < kcnt; ++kk) {
            const int k = kbase + kk;
            fr[3 + 3 * k + 0] = nx[kk];
            fr[3 + 3 * k + 1] = ny[kk];
            fr[3 + 3 * k + 2] = nz[kk];
            const float rx = nx[kk] - cx, ry = ny[kk] - cy, rz = nz[kk] - cz;
            fr[33 + 3 * k + 0] = rx;
            fr[33 + 3 * k + 1] = ry;
            fr[33 + 3 * k + 2] = rz;
            fr[63 + k] = sqrtf(fmaf(rz, rz, fmaf(ry, ry, rx * rx)));
        }

        // quad-reduced mean
        float smx = 0.f, smy = 0.f, smz = 0.f;
        for (int kk = 0; kk < kcnt; ++kk) { smx += nx[kk]; smy += ny[kk]; smz += nz[kk]; }
#define QSUM(v) { v += __shfl_xor(v, 1, 64); v += __shfl_xor(v, 2, 64); }
        QSUM(smx); QSUM(smy); QSUM(smz);
        const float mx = smx * (1.0f / KNN);
        const float my = smy * (1.0f / KNN);
        const float mz = smz * (1.0f / KNN);

        // quad-reduced covariance partials
        float c00 = 0.f, c01 = 0.f, c02 = 0.f, c11 = 0.f, c12 = 0.f, c22 = 0.f;
        for (int kk = 0; kk < kcnt; ++kk) {
            const float ex = nx[kk] - mx, ey = ny[kk] - my, ez = nz[kk] - mz;
            c00 = fmaf(ex, ex, c00); c01 = fmaf(ex, ey, c01); c02 = fmaf(ex, ez, c02);
            c11 = fmaf(ey, ey, c11); c12 = fmaf(ey, ez, c12); c22 = fmaf(ez, ez, c22);
        }
        QSUM(c00); QSUM(c01); QSUM(c02); QSUM(c11); QSUM(c12); QSUM(c22);
#undef QSUM
        const float sc = 1.0f / (KNN - 1);
        c00 *= sc; c01 *= sc; c02 *= sc; c11 *= sc; c12 *= sc; c22 *= sc;

        // fp32 closed-form symmetric 3x3 eigenvalues (all 4 lanes, same time)
        const float qd = (c00 + c11 + c22) * (1.0f / 3.0f);
        const float pp1 = c01 * c01 + c02 * c02 + c12 * c12;
        const float d00 = c00 - qd, d11 = c11 - qd, d22 = c22 - qd;
        const float p2 = d00 * d00 + d11 * d11 + d22 * d22 + 2.0f * pp1;
        float l1, l2, l3;
        if (p2 < 1e-30f) {
            l1 = l2 = l3 = qd;
        } else {
            const float p = sqrtf(p2 * (1.0f / 6.0f));
            const float inv = 1.0f / p;
            const float e00 = d00 * inv, e11 = d11 * inv, e22 = d22 * inv;
            const float e01 = c01 * inv, e02 = c02 * inv, e12 = c12 * inv;
            float detB = e00 * (e11 * e22 - e12 * e12)
                       - e01 * (e01 * e22 - e12 * e02)
                       + e02 * (e01 * e12 - e11 * e02);
            float r = 0.5f * detB;
            r = fminf(1.0f, fmaxf(-1.0f, r));
            const float phi = acosf(r) * (1.0f / 3.0f);
            l1 = qd + 2.0f * p * __cosf(phi);                          // largest
            l3 = qd + 2.0f * p * __cosf(phi + 2.0943951023931953f);    // smallest
            l2 = 3.0f * qd - l1 - l3;
        }
        if (s == 0) {
            fr[73] = (l1 - l2) / l1;
            fr[74] = (l2 - l3) / l1;
            fr[75] = l3 / l1;
        }
    }

    __syncthreads();   // weights + features visible

    const float* fr = fs[pl];
    const int f0 = subf * 38;

    float h[32];
#pragma unroll
    for (int j = 0; j < 32; ++j) h[j] = (subf == 0) ? b1s[subh * 32 + j] : 0.0f;

#pragma unroll 2
    for (int ff = 0; ff < 38; ++ff) {
        const int f = f0 + ff;
        const float v = fr[f];
        const float4* w4 = reinterpret_cast<const float4*>(w1s + f * 68 + subh * 32);
#pragma unroll
        for (int j4 = 0; j4 < 8; ++j4) {
            const float4 w = w4[j4];
            h[4 * j4 + 0] = fmaf(v, w.x, h[4 * j4 + 0]);
            h[4 * j4 + 1] = fmaf(v, w.y, h[4 * j4 + 1]);
            h[4 * j4 + 2] = fmaf(v, w.z, h[4 * j4 + 2]);
            h[4 * j4 + 3] = fmaf(v, w.w, h[4 * j4 + 3]);
        }
    }

    // combine feature halves (lanes differing in bit 1)
#pragma unroll
    for (int j = 0; j < 32; ++j) h[j] += __shfl_xor(h[j], 2, 64);

    float o0 = 0.f, o1 = 0.f, o2 = 0.f;
#pragma unroll
    for (int j = 0; j < 32; ++j) {
        const float r = fmaxf(h[j], 0.0f);
        const int jj = subh * 32 + j;
        o0 = fmaf(r, w2s[jj * 3 + 0], o0);
        o1 = fmaf(r, w2s[jj * 3 + 1], o1);
        o2 = fmaf(r, w2s[jj * 3 + 2], o2);
    }
    // combine hidden halves (lanes differing in bit 0)
    o0 += __shfl_xor(o0, 1, 64);
    o1 += __shfl_xor(o1, 1, 64);
    o2 += __shfl_xor(o2, 1, 64);

    if ((t & 3) == 0) {
        float* op = out + (size_t)gid * 3;
        op[0] = fmaxf(o0 + b2s[0], 0.0f);
        op[1] = fmaxf(o1 + b2s[1], 0.0f);
        op[2] = fmaxf(o2 + b2s[2], 0.0f);
    }
}

extern "C" void kernel_launch(void* const* d_in, const int* in_sizes, int n_in,
                              void* d_out, int out_size, void* d_ws, size_t ws_size,
                              hipStream_t stream) {
    const float* cloud = (const float*)d_in[0];   // [4,8192,3]
    const float* W1    = (const float*)d_in[1];   // [76,64]
    const float* b1    = (const float*)d_in[2];   // [64]
    const float* W2    = (const float*)d_in[3];   // [64,3]
    const float* b2    = (const float*)d_in[4];   // [3]
    float* out = (float*)d_out;                   // [4,8192,3]

    unsigned short* knn = (unsigned short*)d_ws;              // 640 KB
    float* soa   = (float*)((char*)d_ws + 655360);            // 384 KB SoA x/y/z
    float* tau_g = (float*)((char*)d_ws + 655360 + 393216);   // 128 KB tau

    soa_kernel<<<dim3(128), dim3(256), 0, stream>>>(cloud, soa);
    knn_pass1<<<dim3(2048), dim3(256), 0, stream>>>(soa, tau_g);
    knn_pass2<<<dim3(2048), dim3(256), 0, stream>>>(soa, tau_g, knn);
    feat_mlp_kernel<<<dim3(512), dim3(256), 0, stream>>>(cloud, W1, b1, W2, b2, knn, out);
}

// Round 15
// 165.849 us; speedup vs baseline: 1.0395x; 1.0395x over previous
//
#include <hip/hip_runtime.h>
#include <math.h>

#define KNN    10
#define NPTS   8192
#define HID    64
#define NF     76
#define Q      16                // queries per block (one group)
#define CAP    64                // pass-2 collection capacity per query
#define F32_INF __uint_as_float(0x7F800000u)

typedef float v2f __attribute__((ext_vector_type(2)));

__device__ __forceinline__ float rl(float v, int lane) {
    return __int_as_float(__builtin_amdgcn_readlane(__float_as_int(v), lane));
}

// ---------------------------------------------------------------------------
// R24 SoA transpose (kept: candidate loads coalesced).
// ---------------------------------------------------------------------------
__global__ __launch_bounds__(256) void soa_kernel(const float* __restrict__ cloud,
                                                  float* __restrict__ soa) {
    const int i = blockIdx.x * 256 + threadIdx.x;   // 0..32767 (grid exact)
    const float x = cloud[i * 3 + 0];
    const float y = cloud[i * 3 + 1];
    const float z = cloud[i * 3 + 2];
    soa[i]             = x;
    soa[4 * NPTS + i]  = y;
    soa[8 * NPTS + i]  = z;
}

// ---------------------------------------------------------------------------
// R34 = FINAL: exact revert to R32/R29 split (best measured: 166.4/166.7us,
// reproduced twice). R33's margin pre-filter regressed pass2 65->70us (4th
// instance of "adding instructions to a latency-bound loop costs full
// price"); per pre-commitment, pass2 is also at its floor.
// Session ledger: 12 scan/feat experiments null-or-negative, time pinned
// 107-114us across all instruction streams; fusion -26us; occupancy
// immovable at ~34-47% with no countable resource limit. Floor = latency-
// bound split pipeline: soa ~3 + pass1 ~44 + pass2 ~65 + feat_mlp ~50.
// ---------------------------------------------------------------------------
__global__ __launch_bounds__(256) void knn_pass1(const float* __restrict__ soa,
                                                 float* __restrict__ tau_g) {
    __shared__ float pk[4][Q][17];                  // 4.3 KB

    const int t    = threadIdx.x;
    const int w    = t >> 6;                  // wave 0..3 = candidate quarter
    const int lane = t & 63;
    const int bx   = blockIdx.x;              // 0..2047
    const int b    = bx >> 9;                 // batch (512 blocks per batch)
    const int n_base = (bx & 511) * Q;        // batch-local first query
    const int cb0 = w * (NPTS / 4);           // candidate base for this wave

    const float* __restrict__ xs = soa + (size_t)b * NPTS;
    const float* __restrict__ ys = xs + 4 * NPTS;
    const float* __restrict__ zs = xs + 8 * NPTS;

    // ---- query coords -> SGPR pairs via readlane ----
    v2f qx_p[8], qy_p[8], qz_p[8];
    {
        const int ql = n_base + (lane & 15);
        const float lx = xs[ql];
        const float ly = ys[ql];
        const float lz = zs[ql];
#pragma unroll
        for (int j = 0; j < 8; ++j) {
            qx_p[j] = (v2f){ rl(lx, 2 * j), rl(lx, 2 * j + 1) };
            qy_p[j] = (v2f){ rl(ly, 2 * j), rl(ly, 2 * j + 1) };
            qz_p[j] = (v2f){ rl(lz, 2 * j), rl(lz, 2 * j + 1) };
        }
    }

#define LOADT(TI, RX, RY, RZ) do {                        \
        const int c_ = cb0 + (((TI) & 31) * 64) + lane;   \
        (RX) = xs[c_]; (RY) = ys[c_]; (RZ) = zs[c_];      \
    } while (0)

#define P1_BODY(CX, CY, CZ) do {                                          \
        const float aw_ = fmaf((CZ), (CZ), fmaf((CY), (CY), (CX)*(CX)));  \
        const v2f aw2_ = (v2f){ aw_, aw_ };                               \
        const v2f ax2_ = (v2f){ -2.0f * (CX), -2.0f * (CX) };             \
        const v2f ay2_ = (v2f){ -2.0f * (CY), -2.0f * (CY) };             \
        const v2f az2_ = (v2f){ -2.0f * (CZ), -2.0f * (CZ) };             \
        _Pragma("unroll")                                                 \
        for (int j_ = 0; j_ < 8; ++j_) {                                  \
            const v2f v_ = __builtin_elementwise_fma(ax2_, qx_p[j_],      \
                           __builtin_elementwise_fma(ay2_, qy_p[j_],      \
                           __builtin_elementwise_fma(az2_, qz_p[j_], aw2_))); \
            vmin2[j_] = __builtin_elementwise_min(vmin2[j_], v_);         \
        }                                                                 \
    } while (0)

    v2f vmin2[8];
#pragma unroll
    for (int j = 0; j < 8; ++j) vmin2[j] = (v2f){ F32_INF, F32_INF };

    {
        float x0, y0, z0, x1, y1, z1, x2, y2, z2, x3, y3, z3;
        LOADT(0, x0, y0, z0);
        LOADT(1, x1, y1, z1);
        for (int k = 0; k < 32; k += 4) {     // 8 iterations, 4 tiles each
            LOADT(k + 2, x2, y2, z2);
            LOADT(k + 3, x3, y3, z3);
            P1_BODY(x0, y0, z0);
            P1_BODY(x1, y1, z1);
            LOADT(k + 4, x0, y0, z0);         // wraps at tail (dead)
            LOADT(k + 5, x1, y1, z1);
            P1_BODY(x2, y2, z2);
            P1_BODY(x3, y3, z3);
        }
    }

#pragma unroll
    for (int qq = 0; qq < Q; ++qq) {
        float v = vmin2[qq >> 1][qq & 1];
        v = fminf(v, __shfl_xor(v, 32, 64));
        v = fminf(v, __shfl_xor(v, 16, 64));
        if (lane < 16) pk[w][qq][lane] = v;
    }
    __syncthreads();                          // pk visible

    // wave 0: 11th smallest of 64 chunk minima -> tau (exact bits to global)
    if (w == 0) {
        float md[KNN + 1];
#pragma unroll
        for (int s = 0; s <= KNN; ++s) md[s] = F32_INF;
        const int qsel = lane & 15;           // 4-way replicated
#pragma unroll
        for (int cc = 0; cc < 64; ++cc) {
            float d = pk[cc >> 4][qsel][cc & 15];
#pragma unroll
            for (int u = 0; u <= KNN; ++u) {
                const float lo = fminf(md[u], d);
                d = fmaxf(md[u], d);
                md[u] = lo;
            }
        }
        if (lane < 16) tau_g[bx * Q + lane] = md[KNN] + 1e-3f;
    }
#undef LOADT
#undef P1_BODY
}

__global__ __launch_bounds__(256) void knn_pass2(const float* __restrict__ soa,
                                                 const float* __restrict__ tau_g,
                                                 unsigned short* __restrict__ knn_idx) {
    __shared__ unsigned long long coll[CAP][Q + 1]; // 8.5 KB
    __shared__ int cnt[Q];

    const int t    = threadIdx.x;
    const int w    = t >> 6;                  // wave 0..3 = candidate quarter
    const int lane = t & 63;
    const int bx   = blockIdx.x;              // 0..2047
    const int b    = bx >> 9;                 // batch
    const int n_base = (bx & 511) * Q;        // batch-local first query
    const int cb0 = w * (NPTS / 4);           // candidate base for this wave

    const float* __restrict__ xs = soa + (size_t)b * NPTS;
    const float* __restrict__ ys = xs + 4 * NPTS;
    const float* __restrict__ zs = xs + 8 * NPTS;

    if (t < Q) cnt[t] = 0;

    // ---- query coords -> SGPR pairs via readlane ----
    v2f qx_p[8], qy_p[8], qz_p[8];
    {
        const int ql = n_base + (lane & 15);
        const float lx = xs[ql];
        const float ly = ys[ql];
        const float lz = zs[ql];
#pragma unroll
        for (int j = 0; j < 8; ++j) {
            qx_p[j] = (v2f){ rl(lx, 2 * j), rl(lx, 2 * j + 1) };
            qy_p[j] = (v2f){ rl(ly, 2 * j), rl(ly, 2 * j + 1) };
            qz_p[j] = (v2f){ rl(lz, 2 * j), rl(lz, 2 * j + 1) };
        }
    }

    float taum[Q];
    {
        const float tv = tau_g[bx * Q + (lane & 15)];   // exact bits from pass1
#pragma unroll
        for (int qq = 0; qq < Q; ++qq) taum[qq] = rl(tv, qq);   // -> SGPRs
    }
    __syncthreads();                          // cnt zero-init visible

#define LOADT(TI, RX, RY, RZ) do {                        \
        const int c_ = cb0 + (((TI) & 31) * 64) + lane;   \
        (RX) = xs[c_]; (RY) = ys[c_]; (RZ) = zs[c_];      \
    } while (0)

#define P2_BODY(CX, CY, CZ, TI) do {                                      \
        const int jj_ = cb0 + (TI) * 64 + lane;                           \
        const float aw_ = fmaf((CZ), (CZ), fmaf((CY), (CY), (CX)*(CX)));  \
        const v2f aw2_ = (v2f){ aw_, aw_ };                               \
        const v2f ax2_ = (v2f){ -2.0f * (CX), -2.0f * (CX) };             \
        const v2f ay2_ = (v2f){ -2.0f * (CY), -2.0f * (CY) };             \
        const v2f az2_ = (v2f){ -2.0f * (CZ), -2.0f * (CZ) };             \
        _Pragma("unroll")                                                 \
        for (int j_ = 0; j_ < 8; ++j_) {                                  \
            const v2f v_ = __builtin_elementwise_fma(ax2_, qx_p[j_],      \
                           __builtin_elementwise_fma(ay2_, qy_p[j_],      \
                           __builtin_elementwise_fma(az2_, qz_p[j_], aw2_))); \
            _Pragma("unroll")                                             \
            for (int half_ = 0; half_ < 2; ++half_) {                     \
                const int qq_ = 2 * j_ + half_;                           \
                if (__builtin_expect(v_[half_] <= taum[qq_], 0)) {        \
                    const float qx_ = qx_p[j_][half_];                    \
                    const float qy_ = qy_p[j_][half_];                    \
                    const float qz_ = qz_p[j_][half_];                    \
                    const float qs_ = fmaf(qz_, qz_, fmaf(qy_, qy_, qx_ * qx_)); \
                    const float dot_ = fmaf((CZ), qz_, fmaf((CY), qy_, (CX) * qx_)); \
                    const float d2_ = fmaf(-2.0f, dot_, qs_ + aw_);       \
                    const unsigned int fb_ = __float_as_uint(d2_);        \
                    const unsigned int m_ =                               \
                        fb_ ^ ((unsigned int)((int)fb_ >> 31) | 0x80000000u); \
                    const unsigned long long key_ =                       \
                        ((unsigned long long)m_ << 13) | (unsigned long long)(unsigned)jj_; \
                    const int slot_ = atomicAdd(&cnt[qq_], 1);            \
                    if (slot_ < CAP) coll[slot_][qq_] = key_;             \
                }                                                         \
            }                                                             \
        }                                                                 \
    } while (0)

    {
        float x0, y0, z0, x1, y1, z1, x2, y2, z2, x3, y3, z3;
        LOADT(0, x0, y0, z0);
        LOADT(1, x1, y1, z1);
        for (int k = 0; k < 32; k += 4) {
            LOADT(k + 2, x2, y2, z2);
            LOADT(k + 3, x3, y3, z3);
            P2_BODY(x0, y0, z0, k + 0);
            P2_BODY(x1, y1, z1, k + 1);
            LOADT(k + 4, x0, y0, z0);
            LOADT(k + 5, x1, y1, z1);
            P2_BODY(x2, y2, z2, k + 2);
            P2_BODY(x3, y3, z3, k + 3);
        }
    }
    __syncthreads();

    // ---------------- phase 3: top-11 bubble, filter self by index ----------
    if (t < Q) {
        const int m = cnt[t];
        int mc = m;
#pragma unroll
        for (int off = 1; off < 16; off <<= 1)        // 16 active lanes only
            mc = max(mc, __shfl_xor(mc, off, 64));
        mc = __builtin_amdgcn_readfirstlane(mc);

        const int n = (bx & 511) * Q + t;     // this lane's batch-local query

        unsigned long long md[KNN + 1];
#pragma unroll
        for (int s = 0; s <= KNN; ++s) md[s] = ~0ULL;

        if (mc <= CAP) {
            for (int cc = 0; cc < mc; ++cc) {
                unsigned long long key = (cc < m) ? coll[cc][t] : ~0ULL;
#pragma unroll
                for (int u = 0; u <= KNN; ++u) {
                    const bool lt = key < md[u];
                    const unsigned long long lo = lt ? key : md[u];
                    key = lt ? md[u] : key;
                    md[u] = lo;
                }
            }
        } else {
            // exact serial fallback (never expected): full rescan (SoA reads,
            // identical float values)
            const float qx = xs[n];
            const float qy = ys[n];
            const float qz = zs[n];
            const float qs = fmaf(qz, qz, fmaf(qy, qy, qx * qx));
            for (int j = 0; j < NPTS; ++j) {
                const float px = xs[j];
                const float py = ys[j];
                const float pz = zs[j];
                const float pw = fmaf(pz, pz, fmaf(py, py, px * px));
                const float dot = fmaf(pz, qz, fmaf(py, qy, px * qx));
                const float d2 = fmaf(-2.0f, dot, qs + pw);
                const unsigned int fb = __float_as_uint(d2);
                const unsigned int mm =
                    fb ^ ((unsigned int)((int)fb >> 31) | 0x80000000u);
                unsigned long long key =
                    ((unsigned long long)mm << 13) | (unsigned long long)j;
                key = (j == n) ? ~0ULL : key;
#pragma unroll
                for (int u = 0; u <= KNN; ++u) {
                    const bool lt = key < md[u];
                    const unsigned long long lo = lt ? key : md[u];
                    key = lt ? md[u] : key;
                    md[u] = lo;
                }
            }
        }

        unsigned short* outp = knn_idx + ((size_t)b * NPTS + n) * KNN;
        int outc = 0;
#pragma unroll
        for (int u = 0; u <= KNN; ++u) {
            const int idx = (int)(md[u] & 8191u);
            if (outc < KNN && idx != n) outp[outc++] = (unsigned short)idx;
        }
    }
#undef LOADT
#undef P2_BODY
}

// ---------------------------------------------------------------------------
// Features + MLP — R19 quad-parallel form (best measured). Lanes own 3/3/2/2
// neighbors; quad shfl_xor(1,2) reduces; eigen redundant on 4 lanes; MLP =
// R12/R14 layout.
// ---------------------------------------------------------------------------
__global__ __launch_bounds__(256) void feat_mlp_kernel(const float* __restrict__ cloud,
                                                       const float* __restrict__ W1,
                                                       const float* __restrict__ b1,
                                                       const float* __restrict__ W2,
                                                       const float* __restrict__ b2,
                                                       const unsigned short* __restrict__ knn_idx,
                                                       float* __restrict__ out) {
    __shared__ float w1s[NF * 68];            // padded stride
    __shared__ float b1s[HID];
    __shared__ float w2s[HID * 3];
    __shared__ float b2s[3];
    __shared__ float fs[64][NF + 1];          // stride 77

    const int t = threadIdx.x;
    for (int idx = t; idx < NF * HID; idx += 256)
        w1s[(idx >> 6) * 68 + (idx & 63)] = W1[idx];
    if (t < HID) b1s[t] = b1[t];
    if (t < HID * 3) w2s[t] = W2[t];
    if (t < 3) b2s[t] = b2[t];

    const int pl   = t >> 2;                  // point slot 0..63
    const int s    = t & 3;                   // quad sub-lane
    const int subh = t & 1;                   // hidden half
    const int subf = (t >> 1) & 1;            // feature half
    const int gid = blockIdx.x * 64 + pl;     // 0..32767
    const int b = gid >> 13;
    const int n = gid & (NPTS - 1);
    const float* cb = cloud + (size_t)b * NPTS * 3;

    // ---- quad-parallel feature build ----
    {
        const float cx = cb[n * 3 + 0];       // same addr across quad (broadcast)
        const float cy = cb[n * 3 + 1];
        const float cz = cb[n * 3 + 2];

        // neighbor ownership: s=0:{0,1,2} s=1:{3,4,5} s=2:{6,7} s=3:{8,9}
        const int kbase = (s == 0) ? 0 : (s == 1) ? 3 : (s == 2) ? 6 : 8;
        const int kcnt  = (s < 2) ? 3 : 2;

        float nx[3], ny[3], nz[3];
        const unsigned short* ki = knn_idx + (size_t)gid * KNN;
        for (int kk = 0; kk < kcnt; ++kk) {
            const int j = ki[kbase + kk];
            nx[kk] = cb[j * 3 + 0];
            ny[kk] = cb[j * 3 + 1];
            nz[kk] = cb[j * 3 + 2];
        }

        float* fr = fs[pl];
        if (s == 0) { fr[0] = cx; fr[1] = cy; fr[2] = cz; }
        for (int kk = 0; kk < kcnt; ++kk) {
            const int k = kbase + kk;
            fr[3 + 3 * k + 0] = nx[kk];
            fr[3 + 3 * k + 1] = ny[kk];
            fr[3 + 3 * k + 2] = nz[kk];
            const float rx = nx[kk] - cx, ry = ny[kk] - cy, rz = nz[kk] - cz;
            fr[33 + 3 * k + 0] = rx;
            fr[33 + 3 * k + 1] = ry;
            fr[33 + 3 * k + 2] = rz;
            fr[63 + k] = sqrtf(fmaf(rz, rz, fmaf(ry, ry, rx * rx)));
        }

        // quad-reduced mean
        float smx = 0.f, smy = 0.f, smz = 0.f;
        for (int kk = 0; kk < kcnt; ++kk) { smx += nx[kk]; smy += ny[kk]; smz += nz[kk]; }
#define QSUM(v) { v += __shfl_xor(v, 1, 64); v += __shfl_xor(v, 2, 64); }
        QSUM(smx); QSUM(smy); QSUM(smz);
        const float mx = smx * (1.0f / KNN);
        const float my = smy * (1.0f / KNN);
        const float mz = smz * (1.0f / KNN);

        // quad-reduced covariance partials
        float c00 = 0.f, c01 = 0.f, c02 = 0.f, c11 = 0.f, c12 = 0.f, c22 = 0.f;
        for (int kk = 0; kk < kcnt; ++kk) {
            const float ex = nx[kk] - mx, ey = ny[kk] - my, ez = nz[kk] - mz;
            c00 = fmaf(ex, ex, c00); c01 = fmaf(ex, ey, c01); c02 = fmaf(ex, ez, c02);
            c11 = fmaf(ey, ey, c11); c12 = fmaf(ey, ez, c12); c22 = fmaf(ez, ez, c22);
        }
        QSUM(c00); QSUM(c01); QSUM(c02); QSUM(c11); QSUM(c12); QSUM(c22);
#undef QSUM
        const float sc = 1.0f / (KNN - 1);
        c00 *= sc; c01 *= sc; c02 *= sc; c11 *= sc; c12 *= sc; c22 *= sc;

        // fp32 closed-form symmetric 3x3 eigenvalues (all 4 lanes, same time)
        const float qd = (c00 + c11 + c22) * (1.0f / 3.0f);
        const float pp1 = c01 * c01 + c02 * c02 + c12 * c12;
        const float d00 = c00 - qd, d11 = c11 - qd, d22 = c22 - qd;
        const float p2 = d00 * d00 + d11 * d11 + d22 * d22 + 2.0f * pp1;
        float l1, l2, l3;
        if (p2 < 1e-30f) {
            l1 = l2 = l3 = qd;
        } else {
            const float p = sqrtf(p2 * (1.0f / 6.0f));
            const float inv = 1.0f / p;
            const float e00 = d00 * inv, e11 = d11 * inv, e22 = d22 * inv;
            const float e01 = c01 * inv, e02 = c02 * inv, e12 = c12 * inv;
            float detB = e00 * (e11 * e22 - e12 * e12)
                       - e01 * (e01 * e22 - e12 * e02)
                       + e02 * (e01 * e12 - e11 * e02);
            float r = 0.5f * detB;
            r = fminf(1.0f, fmaxf(-1.0f, r));
            const float phi = acosf(r) * (1.0f / 3.0f);
            l1 = qd + 2.0f * p * __cosf(phi);                          // largest
            l3 = qd + 2.0f * p * __cosf(phi + 2.0943951023931953f);    // smallest
            l2 = 3.0f * qd - l1 - l3;
        }
        if (s == 0) {
            fr[73] = (l1 - l2) / l1;
            fr[74] = (l2 - l3) / l1;
            fr[75] = l3 / l1;
        }
    }

    __syncthreads();   // weights + features visible

    const float* fr = fs[pl];
    const int f0 = subf * 38;

    float h[32];
#pragma unroll
    for (int j = 0; j < 32; ++j) h[j] = (subf == 0) ? b1s[subh * 32 + j] : 0.0f;

#pragma unroll 2
    for (int ff = 0; ff < 38; ++ff) {
        const int f = f0 + ff;
        const float v = fr[f];
        const float4* w4 = reinterpret_cast<const float4*>(w1s + f * 68 + subh * 32);
#pragma unroll
        for (int j4 = 0; j4 < 8; ++j4) {
            const float4 w = w4[j4];
            h[4 * j4 + 0] = fmaf(v, w.x, h[4 * j4 + 0]);
            h[4 * j4 + 1] = fmaf(v, w.y, h[4 * j4 + 1]);
            h[4 * j4 + 2] = fmaf(v, w.z, h[4 * j4 + 2]);
            h[4 * j4 + 3] = fmaf(v, w.w, h[4 * j4 + 3]);
        }
    }

    // combine feature halves (lanes differing in bit 1)
#pragma unroll
    for (int j = 0; j < 32; ++j) h[j] += __shfl_xor(h[j], 2, 64);

    float o0 = 0.f, o1 = 0.f, o2 = 0.f;
#pragma unroll
    for (int j = 0; j < 32; ++j) {
        const float r = fmaxf(h[j], 0.0f);
        const int jj = subh * 32 + j;
        o0 = fmaf(r, w2s[jj * 3 + 0], o0);
        o1 = fmaf(r, w2s[jj * 3 + 1], o1);
        o2 = fmaf(r, w2s[jj * 3 + 2], o2);
    }
    // combine hidden halves (lanes differing in bit 0)
    o0 += __shfl_xor(o0, 1, 64);
    o1 += __shfl_xor(o1, 1, 64);
    o2 += __shfl_xor(o2, 1, 64);

    if ((t & 3) == 0) {
        float* op = out + (size_t)gid * 3;
        op[0] = fmaxf(o0 + b2s[0], 0.0f);
        op[1] = fmaxf(o1 + b2s[1], 0.0f);
        op[2] = fmaxf(o2 + b2s[2], 0.0f);
    }
}

extern "C" void kernel_launch(void* const* d_in, const int* in_sizes, int n_in,
                              void* d_out, int out_size, void* d_ws, size_t ws_size,
                              hipStream_t stream) {
    const float* cloud = (const float*)d_in[0];   // [4,8192,3]
    const float* W1    = (const float*)d_in[1];   // [76,64]
    const float* b1    = (const float*)d_in[2];   // [64]
    const float* W2    = (const float*)d_in[3];   // [64,3]
    const float* b2    = (const float*)d_in[4];   // [3]
    float* out = (float*)d_out;                   // [4,8192,3]

    unsigned short* knn = (unsigned short*)d_ws;              // 640 KB
    float* soa   = (float*)((char*)d_ws + 655360);            // 384 KB SoA x/y/z
    float* tau_g = (float*)((char*)d_ws + 655360 + 393216);   // 128 KB tau

    soa_kernel<<<dim3(128), dim3(256), 0, stream>>>(cloud, soa);
    knn_pass1<<<dim3(2048), dim3(256), 0, stream>>>(soa, tau_g);
    knn_pass2<<<dim3(2048), dim3(256), 0, stream>>>(soa, tau_g, knn);
    feat_mlp_kernel<<<dim3(512), dim3(256), 0, stream>>>(cloud, W1, b1, W2, b2, knn, out);
}